// Round 12
// baseline (328.699 us; speedup 1.0000x reference)
//
#include <hip/hip_runtime.h>
#include <hip/hip_bf16.h>
#include <math.h>
#include <stdint.h>

#define B_     16
#define CI_    512
#define CO_    512
#define HH     64
#define WW     64
#define STYLE_ 512

typedef __bf16 bf16x8 __attribute__((ext_vector_type(8)));
typedef float f32x16 __attribute__((ext_vector_type(16)));

// bank swizzle in 16-B slot space: row r (32 B per row = 2 slots), half h.
__device__ __forceinline__ int fsl(int r, int h) {
    return (2 * r + (h ^ ((r >> 2) & 1))) ^ (((r >> 4) & 1) << 1);
}

// ---- workspace layout (bytes) ----
#define WS_S     0                    // s[b][ci] f32, 32 KB
#define WS_DEMOD 32768                // demod[b][co] f32, 32 KB
#define WS_WSQ   65536                // wsq[ci][co] f32, 1 MB
#define WS_WB    1114112              // wb[ci/16][t][slots fsl][8] bf16, 4.7 MB
#define WS_XS    5832704              // xs[ci/16][b][66][slots fsl][8] bf16, 69.2 MB

__device__ __forceinline__ void gload16(const void* g, void* l) {
    __builtin_amdgcn_global_load_lds((const __attribute__((address_space(1))) uint32_t*)g,
                                     (__attribute__((address_space(3))) uint32_t*)l, 16, 0, 0);
}

// ---------- s[b][ci] = style[b] . mod_w[ci] / sqrt(512) + mod_b[ci]  (wave-parallel)
__global__ __launch_bounds__(256) void k_style2(const float* __restrict__ style,
                                                const float* __restrict__ mod_w,
                                                const float* __restrict__ mod_b,
                                                float* __restrict__ s_out) {
    const int ci   = blockIdx.x * 4 + (threadIdx.x >> 6);
    const int b    = blockIdx.y;
    const int lane = threadIdx.x & 63;
    const float4* mw = (const float4*)(mod_w + (size_t)ci * STYLE_);
    const float4* st = (const float4*)(style + (size_t)b * STYLE_);
    float acc = 0.f;
    #pragma unroll
    for (int i = 0; i < 2; ++i) {
        float4 a = mw[lane + i * 64], s = st[lane + i * 64];
        acc += a.x * s.x + a.y * s.y + a.z * s.z + a.w * s.w;
    }
    #pragma unroll
    for (int off = 32; off >= 1; off >>= 1) acc += __shfl_xor(acc, off);
    if (lane == 0)
        s_out[b * CI_ + ci] = acc * 0.044194173824159216f + mod_b[ci];
}

// ---------- wsq[ci][co] = sum_tap w^2  AND  wb: slot fsl(co&127, half) of tap region
__global__ __launch_bounds__(256) void k_wprep(const float* __restrict__ weight,
                                               float* __restrict__ wsq, __bf16* __restrict__ wb) {
    int p = blockIdx.x * 256 + threadIdx.x;   // co*512 + ci
    int co = p >> 9, ci = p & 511;
    const float* wp = weight + (size_t)p * 9;
    const int sl = fsl(co & 127, (ci >> 3) & 1);
    const int gs = ((co >> 7) << 8) + sl;     // global slot within 1024-slot tap region
    float acc = 0.f;
    #pragma unroll
    for (int t = 0; t < 9; ++t) {
        float v = wp[t];
        acc += v * v;
        wb[(((size_t)(ci >> 4) * 9 + t) * 8192) + gs * 8 + (ci & 7)] = (__bf16)v;
    }
    wsq[(size_t)ci * CO_ + co] = acc;
}

// ---------- demod[b][co] = rsqrt(w_scale^2 * sum_ci s^2 * wsq + 1e-8)
__global__ void k_demod(const float* __restrict__ s, const float* __restrict__ wsq,
                        float* __restrict__ demod) {
    int b = blockIdx.x, co = threadIdx.x;
    const float w_scale2 = 1.0f / 4608.0f;
    float acc = 0.f;
    const float* sb = s + b * CI_;
    for (int ci = 0; ci < CI_; ++ci) { float sv = sb[ci]; acc += sv * sv * wsq[(size_t)ci * CO_ + co]; }
    demod[b * CO_ + co] = 1.0f / sqrtf(acc * w_scale2 + 1e-8f);
}

// ---------- xs: row (x+1), half h at global slot fsl(x+1,h)-2  (LDS slot = global+2)
__global__ __launch_bounds__(256) void k_xs(const float* __restrict__ x, const float* __restrict__ s,
                                            __bf16* __restrict__ xs) {
    __shared__ float Lt[64][65];
    const int y = blockIdx.x, b = blockIdx.y;
    const int tid = threadIdx.x;
    const float w_scale = 0.014731391274719739f; // 1/sqrt(512*9)
    for (int ci0 = 0; ci0 < CI_; ci0 += 64) {
        for (int i = tid; i < 64 * 16; i += 256) {     // float4 loads
            int ci = i >> 4, x4 = (i & 15) * 4;
            const float4 v = *(const float4*)&x[((size_t)(b * CI_ + ci0 + ci) * HH + y) * WW + x4];
            float sc = s[b * CI_ + ci0 + ci] * w_scale;
            Lt[ci][x4]     = v.x * sc;
            Lt[ci][x4 + 1] = v.y * sc;
            Lt[ci][x4 + 2] = v.z * sc;
            Lt[ci][x4 + 3] = v.w * sc;
        }
        __syncthreads();
        for (int o = tid; o < 512; o += 256) {
            int xx = o >> 3, oct = o & 7;
            int cb = ci0 + oct * 8;
            int chunk = cb >> 4;
            int pp = fsl(xx + 1, oct & 1) - 2;         // global slot
            bf16x8 v;
            #pragma unroll
            for (int j = 0; j < 8; ++j) v[j] = (__bf16)Lt[oct * 8 + j][xx];
            size_t idx = (((size_t)chunk * 16 + b) * 66 + (y + 1)) * 1024 + pp * 8;
            *(bf16x8*)&xs[idx] = v;
        }
        __syncthreads();
    }
    // guard rows (padded y = 0 and 65) for all 32 chunks (zeros are swizzle-invariant)
    if (y == 0 || y == 63) {
        const int row = (y == 0) ? 0 : 65;
        uint32_t* xs32 = (uint32_t*)xs;
        for (int c = 0; c < 32; ++c)
            for (int i = tid; i < 512; i += 256)
                xs32[(((size_t)c * 16 + b) * 66 + row) * 512 + i] = 0;
    }
}

// ---------- conv: 32x32x16 MFMA, CK=16, dbuf + counted vmcnt + setprio + reg-pipelined taps
// 512 blocks; XCD remap: r8=bid&7, q=bid>>3; co0=(q&3)*128, yb=(q>>2)|(r8<<4)
// 512 thr / 8 waves; wave w: 128co x 1y x 64x; acc 4mi x 2nt x f32x16
// X rowblock stride 2560 B: [halo slots 0,1][body slots 2..129][halo 130,131][pad]
#define XBUF 25600   // 10 * 2560
#define WBUF 36864   // 9 * 128 * 32

__global__ __launch_bounds__(512, 1) void k_conv(
    const __bf16* __restrict__ xs, const __bf16* __restrict__ wb,
    const float* __restrict__ demod, float* __restrict__ out)
{
    __shared__ __align__(512) char smem[2 * XBUF + 2 * WBUF];

    const int tid  = threadIdx.x;
    const int lane = tid & 63;
    const int wave = tid >> 6;

    const int bid  = blockIdx.x;
    const int r8   = bid & 7;            // XCD
    const int q    = bid >> 3;
    const int co0  = (q & 3) * 128;
    const int yb   = (q >> 2) | (r8 << 4);
    const int y0   = (yb & 7) * 8;
    const int b    = yb >> 3;

    const int lm = lane & 31;
    const int g2 = lane >> 5;

    // zero X halo slots (0,1 and 130,131) of 10 rowblocks in BOTH X buffers: 320 dwords
    if (tid < 320) {
        int buf = tid / 160, rem = tid % 160;
        int rb = rem >> 4, hh = rem & 15;
        int side = hh >> 3, dw = hh & 7;
        ((uint32_t*)smem)[buf * (XBUF / 4) + rb * 640 + side * 520 + dw] = 0;
    }
    asm volatile("s_waitcnt lgkmcnt(0)" ::: "memory");

    // ---- staging offsets (chunk-invariant; DMA linear, global pre-swizzled)
    uint32_t soff[9];   // global element offsets
    uint32_t sdst[9];   // LDS byte offsets within selected buffer
    if (wave < 4) {
        #pragma unroll
        for (int i = 0; i < 5; ++i) {
            int j = wave * 5 + i, rb = j >> 1, seg = j & 1;
            soff[i] = (uint32_t)((y0 + rb) * 1024 + seg * 512 + lane * 8);
            sdst[i] = (uint32_t)(rb * 2560 + 32 + seg * 1024 + lane * 16);
        }
    } else {
        #pragma unroll
        for (int i = 0; i < 9; ++i) {
            int j = (wave - 4) * 9 + i;
            int tap = j >> 2, seg = j & 3;
            soff[i] = (uint32_t)(tap * 8192 + co0 * 16 + seg * 512 + lane * 8);
            sdst[i] = (uint32_t)(j * 1024 + lane * 16);
        }
    }

    // ---- compute-read bases (fsl swizzle; fsl(r+32)=fsl(r)+64 keeps +1024 B tricks valid)
    const uint32_t abase = (uint32_t)(16 * fsl(lm, g2));           // + tap*4096 + mi*1024
    uint32_t bbase[9];
    #pragma unroll
    for (int kh = 0; kh < 3; ++kh)
        #pragma unroll
        for (int kw = 0; kw < 3; ++kw)
            bbase[kh * 3 + kw] = (uint32_t)((wave + kh) * 2560 + 16 * fsl(lm + kw, g2));

    f32x16 acc[4][2];
    #pragma unroll
    for (int mi = 0; mi < 4; ++mi)
        #pragma unroll
        for (int nt = 0; nt < 2; ++nt)
            #pragma unroll
            for (int r = 0; r < 16; ++r) acc[mi][nt][r] = 0.f;

    auto stage = [&](int chunk, int sel) {
        if (wave < 4) {
            const __bf16* base = xs + (size_t)chunk * 1081344 + (size_t)b * 67584;
            #pragma unroll
            for (int i = 0; i < 5; ++i) gload16(base + soff[i], smem + sel * XBUF + sdst[i]);
        } else {
            const __bf16* base = wb + (size_t)chunk * 73728;
            #pragma unroll
            for (int i = 0; i < 9; ++i) gload16(base + soff[i], smem + 2 * XBUF + sel * WBUF + sdst[i]);
        }
    };

    stage(0, 0);

    for (int t = 0; t < 32; ++t) {
        if (t < 31) {
            stage(t + 1, (t + 1) & 1);
            if (wave < 4) asm volatile("s_waitcnt vmcnt(5)" ::: "memory");
            else          asm volatile("s_waitcnt vmcnt(9)" ::: "memory");
        } else {
            asm volatile("s_waitcnt vmcnt(0)" ::: "memory");
        }
        __builtin_amdgcn_s_barrier();

        const char* xbuf = smem + (t & 1) * XBUF;
        const char* wbuf = smem + 2 * XBUF + (t & 1) * WBUF + abase;

        // ---- register-pipelined tap loop: issue tap+1's 6 ds_reads before tap's 8 MFMAs
        bf16x8 fa[2][4];
        bf16x8 fb[2][2];
        #pragma unroll
        for (int mi = 0; mi < 4; ++mi) fa[0][mi] = *(const bf16x8*)(wbuf + mi * 1024);
        #pragma unroll
        for (int nt = 0; nt < 2; ++nt) fb[0][nt] = *(const bf16x8*)(xbuf + bbase[0] + nt * 1024);

        __builtin_amdgcn_s_setprio(1);
        #pragma unroll
        for (int tp = 0; tp < 9; ++tp) {
            const int cur = tp & 1, nxt = cur ^ 1;
            if (tp < 8) {
                const char* wp = wbuf + (tp + 1) * 4096;
                #pragma unroll
                for (int mi = 0; mi < 4; ++mi) fa[nxt][mi] = *(const bf16x8*)(wp + mi * 1024);
                #pragma unroll
                for (int nt = 0; nt < 2; ++nt) fb[nxt][nt] = *(const bf16x8*)(xbuf + bbase[tp + 1] + nt * 1024);
            }
            __builtin_amdgcn_sched_barrier(0);   // pin: next-tap loads issued above MFMAs
            #pragma unroll
            for (int nt = 0; nt < 2; ++nt) {
                acc[0][nt] = __builtin_amdgcn_mfma_f32_32x32x16_bf16(fa[cur][0], fb[cur][nt], acc[0][nt], 0, 0, 0);
                acc[1][nt] = __builtin_amdgcn_mfma_f32_32x32x16_bf16(fa[cur][1], fb[cur][nt], acc[1][nt], 0, 0, 0);
                acc[2][nt] = __builtin_amdgcn_mfma_f32_32x32x16_bf16(fa[cur][2], fb[cur][nt], acc[2][nt], 0, 0, 0);
                acc[3][nt] = __builtin_amdgcn_mfma_f32_32x32x16_bf16(fa[cur][3], fb[cur][nt], acc[3][nt], 0, 0, 0);
            }
            __builtin_amdgcn_sched_barrier(0);
        }
        __builtin_amdgcn_s_setprio(0);
        __builtin_amdgcn_s_barrier();
    }

    // ---- epilogue: out[b][co][y][x] = acc * demod; D row=(reg&3)+8*(reg>>2)+4*g2, col=lm
    const int y = y0 + wave;
    float* outb = out + (size_t)b * CO_ * 4096 + (size_t)y * 64;
    #pragma unroll
    for (int mi = 0; mi < 4; ++mi) {
        #pragma unroll
        for (int reg = 0; reg < 16; ++reg) {
            const int co = co0 + mi * 32 + (reg & 3) + 8 * (reg >> 2) + 4 * g2;
            const float dm = demod[b * CO_ + co];
            outb[(size_t)co * 4096 + lm]      = acc[mi][0][reg] * dm;
            outb[(size_t)co * 4096 + 32 + lm] = acc[mi][1][reg] * dm;
        }
    }
}

extern "C" void kernel_launch(void* const* d_in, const int* in_sizes, int n_in,
                              void* d_out, int out_size, void* d_ws, size_t ws_size,
                              hipStream_t stream) {
    const float* x      = (const float*)d_in[0];
    const float* style  = (const float*)d_in[1];
    const float* weight = (const float*)d_in[2];
    const float* mod_w  = (const float*)d_in[3];
    const float* mod_b  = (const float*)d_in[4];
    float* out = (float*)d_out;

    char* wsb = (char*)d_ws;
    float*  s_buf = (float*)(wsb + WS_S);
    float*  demod = (float*)(wsb + WS_DEMOD);
    float*  wsq   = (float*)(wsb + WS_WSQ);
    __bf16* wb    = (__bf16*)(wsb + WS_WB);
    __bf16* xs    = (__bf16*)(wsb + WS_XS);

    k_style2<<<dim3(CI_ / 4, B_), dim3(256), 0, stream>>>(style, mod_w, mod_b, s_buf);
    k_wprep<<<dim3(CO_ * CI_ / 256), dim3(256), 0, stream>>>(weight, wsq, wb);
    k_demod<<<dim3(B_), dim3(CO_), 0, stream>>>(s_buf, wsq, demod);
    k_xs<<<dim3(HH, B_), dim3(256), 0, stream>>>(x, s_buf, xs);
    k_conv<<<dim3(512), dim3(512), 0, stream>>>(xs, wb, demod, out);
}

// Round 13
// 319.741 us; speedup vs baseline: 1.0280x; 1.0280x over previous
//
#include <hip/hip_runtime.h>
#include <hip/hip_bf16.h>
#include <math.h>
#include <stdint.h>

#define B_     16
#define CI_    512
#define CO_    512
#define HH     64
#define WW     64
#define STYLE_ 512

typedef __bf16 bf16x8 __attribute__((ext_vector_type(8)));
typedef float f32x16 __attribute__((ext_vector_type(16)));

// bank swizzle in 16-B slot space: row r (32 B per row = 2 slots), half h.
__device__ __forceinline__ int fsl(int r, int h) {
    return (2 * r + (h ^ ((r >> 2) & 1))) ^ (((r >> 4) & 1) << 1);
}

// ---- workspace layout (bytes) ----
#define WS_S     0                    // s[b][ci] f32, 32 KB
#define WS_DEMOD 32768                // demod[b][co] f32, 32 KB
#define WS_WSQ   65536                // wsq[ci][co] f32, 1 MB
#define WS_WB    1114112              // wb[ci/16][t][slots fsl per 64co tile][8] bf16, 4.7 MB
#define WS_XS    5832704              // xs[ci/16][b][66][slots fsl][8] bf16, 69.2 MB

__device__ __forceinline__ void gload16(const void* g, void* l) {
    __builtin_amdgcn_global_load_lds((const __attribute__((address_space(1))) uint32_t*)g,
                                     (__attribute__((address_space(3))) uint32_t*)l, 16, 0, 0);
}

// ---------- s[b][ci] = style[b] . mod_w[ci] / sqrt(512) + mod_b[ci]  (wave-parallel)
__global__ __launch_bounds__(256) void k_style2(const float* __restrict__ style,
                                                const float* __restrict__ mod_w,
                                                const float* __restrict__ mod_b,
                                                float* __restrict__ s_out) {
    const int ci   = blockIdx.x * 4 + (threadIdx.x >> 6);
    const int b    = blockIdx.y;
    const int lane = threadIdx.x & 63;
    const float4* mw = (const float4*)(mod_w + (size_t)ci * STYLE_);
    const float4* st = (const float4*)(style + (size_t)b * STYLE_);
    float acc = 0.f;
    #pragma unroll
    for (int i = 0; i < 2; ++i) {
        float4 a = mw[lane + i * 64], s = st[lane + i * 64];
        acc += a.x * s.x + a.y * s.y + a.z * s.z + a.w * s.w;
    }
    #pragma unroll
    for (int off = 32; off >= 1; off >>= 1) acc += __shfl_xor(acc, off);
    if (lane == 0)
        s_out[b * CI_ + ci] = acc * 0.044194173824159216f + mod_b[ci];
}

// ---------- wsq[ci][co] = sum_tap w^2  AND  wb: slot (co>>6)*128 + fsl(co&63, half)
__global__ __launch_bounds__(256) void k_wprep(const float* __restrict__ weight,
                                               float* __restrict__ wsq, __bf16* __restrict__ wb) {
    int p = blockIdx.x * 256 + threadIdx.x;   // co*512 + ci
    int co = p >> 9, ci = p & 511;
    const float* wp = weight + (size_t)p * 9;
    const int gs = ((co >> 6) << 7) + fsl(co & 63, (ci >> 3) & 1);  // slot in 1024-slot tap region
    float acc = 0.f;
    #pragma unroll
    for (int t = 0; t < 9; ++t) {
        float v = wp[t];
        acc += v * v;
        wb[(((size_t)(ci >> 4) * 9 + t) * 8192) + gs * 8 + (ci & 7)] = (__bf16)v;
    }
    wsq[(size_t)ci * CO_ + co] = acc;
}

// ---------- demod[b][co] = rsqrt(w_scale^2 * sum_ci s^2 * wsq + 1e-8)
__global__ void k_demod(const float* __restrict__ s, const float* __restrict__ wsq,
                        float* __restrict__ demod) {
    int b = blockIdx.x, co = threadIdx.x;
    const float w_scale2 = 1.0f / 4608.0f;
    float acc = 0.f;
    const float* sb = s + b * CI_;
    for (int ci = 0; ci < CI_; ++ci) { float sv = sb[ci]; acc += sv * sv * wsq[(size_t)ci * CO_ + co]; }
    demod[b * CO_ + co] = 1.0f / sqrtf(acc * w_scale2 + 1e-8f);
}

// ---------- xs: row (x+1), half h at global slot fsl(x+1,h)-2  (LDS slot = global+2)
__global__ __launch_bounds__(256) void k_xs(const float* __restrict__ x, const float* __restrict__ s,
                                            __bf16* __restrict__ xs) {
    __shared__ float Lt[64][65];
    const int y = blockIdx.x, b = blockIdx.y;
    const int tid = threadIdx.x;
    const float w_scale = 0.014731391274719739f; // 1/sqrt(512*9)
    for (int ci0 = 0; ci0 < CI_; ci0 += 64) {
        for (int i = tid; i < 64 * 16; i += 256) {     // float4 loads
            int ci = i >> 4, x4 = (i & 15) * 4;
            const float4 v = *(const float4*)&x[((size_t)(b * CI_ + ci0 + ci) * HH + y) * WW + x4];
            float sc = s[b * CI_ + ci0 + ci] * w_scale;
            Lt[ci][x4]     = v.x * sc;
            Lt[ci][x4 + 1] = v.y * sc;
            Lt[ci][x4 + 2] = v.z * sc;
            Lt[ci][x4 + 3] = v.w * sc;
        }
        __syncthreads();
        for (int o = tid; o < 512; o += 256) {
            int xx = o >> 3, oct = o & 7;
            int cb = ci0 + oct * 8;
            int chunk = cb >> 4;
            int pp = fsl(xx + 1, oct & 1) - 2;         // global slot
            bf16x8 v;
            #pragma unroll
            for (int j = 0; j < 8; ++j) v[j] = (__bf16)Lt[oct * 8 + j][xx];
            size_t idx = (((size_t)chunk * 16 + b) * 66 + (y + 1)) * 1024 + pp * 8;
            *(bf16x8*)&xs[idx] = v;
        }
        __syncthreads();
    }
    // guard rows (padded y = 0 and 65) for all 32 chunks (zeros are swizzle-invariant)
    if (y == 0 || y == 63) {
        const int row = (y == 0) ? 0 : 65;
        uint32_t* xs32 = (uint32_t*)xs;
        for (int c = 0; c < 32; ++c)
            for (int i = tid; i < 512; i += 256)
                xs32[(((size_t)c * 16 + b) * 66 + row) * 512 + i] = 0;
    }
}

// ---------- conv: 32x32x16 MFMA, CK=16, 2 blocks/CU (overlap), dbuf + counted vmcnt
// 1024 blocks; XCD remap: r8=bid&7, q=bid>>3; co0=(q&7)*64, t=q>>3: y0=(t&7)*8, b=r8*2+(t>>3)
// 256 thr / 4 waves; wave w: 64co x 2y(=y0+2w..+1) x 64x; acc 2mi x (2ys x 2nt) f32x16
// X rowblock stride 2112 B: [halo slots 0,1][body 2..129][halo 130,131]; W 9 taps x 2048 B
#define XBUF 21120   // 10 * 2112
#define WBUF 18432   // 9 * 64 * 32

__global__ __launch_bounds__(256, 2) void k_conv(
    const __bf16* __restrict__ xs, const __bf16* __restrict__ wb,
    const float* __restrict__ demod, float* __restrict__ out)
{
    __shared__ __align__(128) char smem[2 * XBUF + 2 * WBUF];

    const int tid  = threadIdx.x;
    const int lane = tid & 63;
    const int wave = tid >> 6;

    const int bid  = blockIdx.x;
    const int r8   = bid & 7;            // XCD
    const int q    = bid >> 3;
    const int co0  = (q & 7) * 64;
    const int tt   = q >> 3;             // 0..15
    const int y0   = (tt & 7) * 8;
    const int b    = r8 * 2 + (tt >> 3);

    const int lm = lane & 31;
    const int g2 = lane >> 5;

    // zero X halo slots (0,1 and 130,131) of 10 rowblocks in BOTH X buffers: 320 dwords
    for (int i = tid; i < 320; i += 256) {
        int buf = i / 160, rem = i % 160;
        int rb = rem >> 4, hh = rem & 15;
        int side = hh >> 3, dw = hh & 7;
        ((uint32_t*)smem)[buf * (XBUF / 4) + rb * 528 + side * 520 + dw] = 0;
    }
    asm volatile("s_waitcnt lgkmcnt(0)" ::: "memory");

    // ---- staging offsets (chunk-invariant; DMA linear, global pre-swizzled)
    uint32_t soff[10];  // global element offsets
    uint32_t sdst[10];  // LDS byte offsets within selected buffer
    if (wave < 2) {
        #pragma unroll
        for (int i = 0; i < 10; ++i) {
            int j = wave * 10 + i, rb = j >> 1, seg = j & 1;
            soff[i] = (uint32_t)((y0 + rb) * 1024 + seg * 512 + lane * 8);
            sdst[i] = (uint32_t)(rb * 2112 + 32 + seg * 1024 + lane * 16);
        }
    } else {
        #pragma unroll
        for (int i = 0; i < 9; ++i) {
            int j = (wave - 2) * 9 + i;          // 0..17
            int tap = j >> 1, seg = j & 1;
            soff[i] = (uint32_t)(tap * 8192 + co0 * 16 + seg * 512 + lane * 8);
            sdst[i] = (uint32_t)(j * 1024 + lane * 16);
        }
        soff[9] = 0; sdst[9] = 0;   // unused
    }

    // ---- compute-read bases
    const uint32_t acol = (uint32_t)(16 * fsl(lm, g2));   // + tap*2048 + mi*1024
    uint32_t cbase[3];
    #pragma unroll
    for (int kw = 0; kw < 3; ++kw) cbase[kw] = (uint32_t)(16 * fsl(lm + kw, g2));
    uint32_t rbase[4];
    #pragma unroll
    for (int rr = 0; rr < 4; ++rr) rbase[rr] = (uint32_t)((2 * wave + rr) * 2112);

    f32x16 acc[2][4];   // [mi][ys*2+nt]
    #pragma unroll
    for (int mi = 0; mi < 2; ++mi)
        #pragma unroll
        for (int n = 0; n < 4; ++n)
            #pragma unroll
            for (int r = 0; r < 16; ++r) acc[mi][n][r] = 0.f;

    auto stage = [&](int chunk, int sel) {
        if (wave < 2) {
            const __bf16* base = xs + (size_t)chunk * 1081344 + (size_t)b * 67584;
            #pragma unroll
            for (int i = 0; i < 10; ++i) gload16(base + soff[i], smem + sel * XBUF + sdst[i]);
        } else {
            const __bf16* base = wb + (size_t)chunk * 73728;
            #pragma unroll
            for (int i = 0; i < 9; ++i) gload16(base + soff[i], smem + 2 * XBUF + sel * WBUF + sdst[i]);
        }
    };

    stage(0, 0);

    for (int t = 0; t < 32; ++t) {
        if (t < 31) {
            stage(t + 1, (t + 1) & 1);
            if (wave < 2) asm volatile("s_waitcnt vmcnt(10)" ::: "memory");
            else          asm volatile("s_waitcnt vmcnt(9)"  ::: "memory");
        } else {
            asm volatile("s_waitcnt vmcnt(0)" ::: "memory");
        }
        __builtin_amdgcn_s_barrier();

        const char* xbuf = smem + (t & 1) * XBUF;
        const char* wbuf = smem + 2 * XBUF + (t & 1) * WBUF + acol;

        __builtin_amdgcn_s_setprio(1);
        #pragma unroll
        for (int kw = 0; kw < 3; ++kw) {
            // 6 A-frags (kh x mi) + 8 B-frags (row x nt), rows shared across (kh,ys)
            bf16x8 fa[3][2], fb[4][2];
            #pragma unroll
            for (int kh = 0; kh < 3; ++kh) {
                const char* wp = wbuf + (kh * 3 + kw) * 2048;
                fa[kh][0] = *(const bf16x8*)(wp);
                fa[kh][1] = *(const bf16x8*)(wp + 1024);
            }
            #pragma unroll
            for (int rr = 0; rr < 4; ++rr) {
                fb[rr][0] = *(const bf16x8*)(xbuf + rbase[rr] + cbase[kw]);
                fb[rr][1] = *(const bf16x8*)(xbuf + rbase[rr] + cbase[kw] + 1024);
            }
            #pragma unroll
            for (int kh = 0; kh < 3; ++kh)
                #pragma unroll
                for (int ys = 0; ys < 2; ++ys)
                    #pragma unroll
                    for (int nt = 0; nt < 2; ++nt) {
                        acc[0][ys * 2 + nt] = __builtin_amdgcn_mfma_f32_32x32x16_bf16(
                            fa[kh][0], fb[ys + kh][nt], acc[0][ys * 2 + nt], 0, 0, 0);
                        acc[1][ys * 2 + nt] = __builtin_amdgcn_mfma_f32_32x32x16_bf16(
                            fa[kh][1], fb[ys + kh][nt], acc[1][ys * 2 + nt], 0, 0, 0);
                    }
        }
        __builtin_amdgcn_s_setprio(0);
        __builtin_amdgcn_s_barrier();
    }

    // ---- epilogue: out[b][co][y][x] = acc * demod; D row=(reg&3)+8*(reg>>2)+4*g2, col=lm
    #pragma unroll
    for (int mi = 0; mi < 2; ++mi) {
        #pragma unroll
        for (int ys = 0; ys < 2; ++ys) {
            const int y = y0 + 2 * wave + ys;
            float* outb = out + ((size_t)b * CO_ + co0 + mi * 32) * 4096 + (size_t)y * 64;
            #pragma unroll
            for (int reg = 0; reg < 16; ++reg) {
                const int cosub = (reg & 3) + 8 * (reg >> 2) + 4 * g2;
                const float dm = demod[b * CO_ + co0 + mi * 32 + cosub];
                outb[(size_t)cosub * 4096 + lm]      = acc[mi][ys * 2 + 0][reg] * dm;
                outb[(size_t)cosub * 4096 + 32 + lm] = acc[mi][ys * 2 + 1][reg] * dm;
            }
        }
    }
}

extern "C" void kernel_launch(void* const* d_in, const int* in_sizes, int n_in,
                              void* d_out, int out_size, void* d_ws, size_t ws_size,
                              hipStream_t stream) {
    const float* x      = (const float*)d_in[0];
    const float* style  = (const float*)d_in[1];
    const float* weight = (const float*)d_in[2];
    const float* mod_w  = (const float*)d_in[3];
    const float* mod_b  = (const float*)d_in[4];
    float* out = (float*)d_out;

    char* wsb = (char*)d_ws;
    float*  s_buf = (float*)(wsb + WS_S);
    float*  demod = (float*)(wsb + WS_DEMOD);
    float*  wsq   = (float*)(wsb + WS_WSQ);
    __bf16* wb    = (__bf16*)(wsb + WS_WB);
    __bf16* xs    = (__bf16*)(wsb + WS_XS);

    k_style2<<<dim3(CI_ / 4, B_), dim3(256), 0, stream>>>(style, mod_w, mod_b, s_buf);
    k_wprep<<<dim3(CO_ * CI_ / 256), dim3(256), 0, stream>>>(weight, wsq, wb);
    k_demod<<<dim3(B_), dim3(CO_), 0, stream>>>(s_buf, wsq, demod);
    k_xs<<<dim3(HH, B_), dim3(256), 0, stream>>>(x, s_buf, xs);
    k_conv<<<dim3(1024), dim3(256), 0, stream>>>(xs, wb, demod, out);
}